// Round 10
// baseline (2909.567 us; speedup 1.0000x reference)
//
#include <hip/hip_runtime.h>
#include <stdint.h>

typedef unsigned long long u64;
typedef unsigned int u32;
typedef float f2 __attribute__((ext_vector_type(2)));

__device__ __forceinline__ float rn_mul(float a, float b){ return __fmul_rn(a,b); }
__device__ __forceinline__ float rn_add(float a, float b){ return __fadd_rn(a,b); }
__device__ __forceinline__ float rn_sub(float a, float b){ return __fsub_rn(a,b); }

// monotone float->uint key (for knn; handles tiny negative cancellation)
__device__ __forceinline__ u32 fkey(float d){
  u32 b = __float_as_uint(d);
  return b ^ ((u32)((int)b >> 31) | 0x80000000u);
}

__device__ __forceinline__ u64 shfl_xor64(u64 v, int mask){
  int lo = __shfl_xor((int)(u32)v, mask, 64);
  int hi = __shfl_xor((int)(u32)(v >> 32), mask, 64);
  return ((u64)(u32)hi << 32) | (u32)lo;
}
__device__ __forceinline__ u64 umin64(u64 a, u64 b){ return a < b ? a : b; }
__device__ __forceinline__ u64 umax64(u64 a, u64 b){ return a > b ? a : b; }

// ---- DPP max reductions (VALU pipe; validated r3-r9, absmax 0.0) ----------
template<int C>
__device__ __forceinline__ u32 dstep(u32 v){
  u32 x = (u32)__builtin_amdgcn_update_dpp((int)v, (int)v, C, 0xF, 0xF, false);
  return x > v ? x : v;
}
// full-wave u32 max -> uniform (valid for non-negative float bits too)
__device__ __forceinline__ u32 wave64_maxu(u32 v){
  v = dstep<0x111>(v); v = dstep<0x112>(v); v = dstep<0x114>(v);
  v = dstep<0x118>(v); v = dstep<0x142>(v); v = dstep<0x143>(v);
  return (u32)__builtin_amdgcn_readlane((int)v, 63);
}
template<int C>
__device__ __forceinline__ u64 dstep64(u64 v){
  const u32 l = (u32)__builtin_amdgcn_update_dpp((int)(u32)v, (int)(u32)v, C, 0xF, 0xF, false);
  const u32 h = (u32)__builtin_amdgcn_update_dpp((int)(u32)(v>>32), (int)(u32)(v>>32), C, 0xF, 0xF, false);
  const u64 o = ((u64)h << 32) | l;
  return o > v ? o : v;
}
__device__ __forceinline__ u64 readlane64(u64 v, int l){
  const u32 lo = (u32)__builtin_amdgcn_readlane((int)(u32)v, l);
  const u32 hi = (u32)__builtin_amdgcn_readlane((int)(u32)(v>>32), l);
  return ((u64)hi << 32) | lo;
}
__device__ __forceinline__ f2 f2max(f2 a, f2 b){
  f2 r; r.x = fmaxf(a.x,b.x); r.y = fmaxf(a.y,b.y); return r;
}

// ---------------------------------------------------------------------------
// FPS: one block/batch, NT=512, 16 pts/thread f2-packed. Winner COORDS travel
// inside the per-wave partial (selected from registers during the tie scan),
// so the post-barrier path is: read partial (pk + coords) -> 3-step DPP red8
// -> ballot + s_ff1 + 3 dynamic readlane -- no second dependent LDS read.
// Tie semantics = jnp.argmax (max value bits, min original index) exactly;
// minds are sums of squares (>= +0.0) so u32 order == float order.
// No global memory ops in the loop; winners to LDS u16 list, epilogue store.
// ---------------------------------------------------------------------------
template<int N, int NT, int M>
__global__ __launch_bounds__(NT)
void fps_kernel(const float* __restrict__ pts, float* __restrict__ npts)
{
#pragma clang fp contract(off)
  constexpr int PPT = N / NT;          // 16
  constexpr int PP2 = PPT / 2;         // 8
  constexpr int NW  = NT / 64;         // 8
  __shared__ float4 sp[N];             // coord table (init + epilogue only)
  __shared__ unsigned short WX[M];     // winner idx per selection
  __shared__ u64 ppk[2][NW];           // per-wave pack partials (parity)
  __shared__ float4 pcd[2][NW];        // per-wave winner coords (parity)
  const int b = blockIdx.x;
  const float* P = pts + (size_t)b * N * 3;
  float* O = npts + (size_t)b * M * 3;
  const int tid = threadIdx.x, lane = tid & 63, wv = tid >> 6;

  for (int i = tid; i < N; i += NT)
    sp[i] = make_float4(P[3*i+0], P[3*i+1], P[3*i+2], 0.0f);
  if (tid == 0) WX[0] = 0;
  __syncthreads();

  f2 rx[PP2], ry[PP2], rz[PP2], mind[PP2];
  const float4 c0 = sp[0];
  {
    const f2 cx2 = {c0.x,c0.x}, cy2 = {c0.y,c0.y}, cz2 = {c0.z,c0.z};
#pragma unroll
    for (int j = 0; j < PP2; ++j){
      const float4 va = sp[tid + (2*j+0)*NT];
      const float4 vb = sp[tid + (2*j+1)*NT];
      rx[j] = f2{va.x, vb.x}; ry[j] = f2{va.y, vb.y}; rz[j] = f2{va.z, vb.z};
      const f2 dx = rx[j]-cx2, dy = ry[j]-cy2, dz = rz[j]-cz2;
      mind[j] = ((dx*dx) + (dy*dy)) + (dz*dz);   // v_pk_*, IEEE rn
    }
  }

#define VALK(k) (((k)&1) ? mind[(k)>>1].y : mind[(k)>>1].x)
#define XK(A,k) (((k)&1) ? A[(k)>>1].y : A[(k)>>1].x)

  // local tree-max -> wave value max -> tie scan selecting (min gidx, coords)
  // -> wave index max -> unique winner lane publishes (pk, coords) to slot
#define EXPUB(slot)                                                           \
  {                                                                           \
    f2 t[PP2];                                                                \
    _Pragma("unroll")                                                         \
    for (int j = 0; j < PP2; ++j) t[j] = mind[j];                             \
    _Pragma("unroll")                                                         \
    for (int s = PP2/2; s > 0; s >>= 1)                                       \
      for (int i = 0; i < s; ++i) t[i] = f2max(t[i], t[i+s]);                 \
    const float bm = fmaxf(t[0].x, t[0].y);                                   \
    const u32 wk = wave64_maxu(__float_as_uint(bm));                          \
    u32 mo = 0xFFFFFFFFu;                                                     \
    float ccx = 0.f, ccy = 0.f, ccz = 0.f;                                    \
    _Pragma("unroll")                                                         \
    for (int k = PPT-1; k >= 0; --k){                                         \
      const bool m_ = (__float_as_uint(VALK(k)) == wk);                       \
      mo  = m_ ? (u32)(tid + k*NT) : mo;                                      \
      ccx = m_ ? XK(rx,k) : ccx;                                              \
      ccy = m_ ? XK(ry,k) : ccy;                                              \
      ccz = m_ ? XK(rz,k) : ccz;                                              \
    }                                                                         \
    const u32 wc = wave64_maxu(~mo);                                          \
    if (~mo == wc){   /* unique min-gidx lane of this wave */                 \
      ppk[slot][wv] = ((u64)wk << 32) | (u64)wc;                              \
      pcd[slot][wv] = make_float4(ccx, ccy, ccz, 0.f);                        \
    }                                                                         \
  }

  EXPUB(1)

  for (int it = 1; it < M; ++it){
    __syncthreads();                   // LDS-only loop
    const int p = it & 1;
    const u64 pk = ppk[p][lane & (NW-1)];
    const float4 cc = pcd[p][lane & (NW-1)];
    u64 v = pk;
    v = dstep64<0x111>(v); v = dstep64<0x112>(v); v = dstep64<0x114>(v);
    const u64 g1 = readlane64(v, 7);
    if (tid == 0) WX[it] = (unsigned short)(~(u32)g1);
    const u64 mask = __ballot(pk == g1);
    const int l = __ffsll((unsigned long long)mask) - 1;
    const float cx = __uint_as_float((u32)__builtin_amdgcn_readlane((int)__float_as_uint(cc.x), l));
    const float cy = __uint_as_float((u32)__builtin_amdgcn_readlane((int)__float_as_uint(cc.y), l));
    const float cz = __uint_as_float((u32)__builtin_amdgcn_readlane((int)__float_as_uint(cc.z), l));
    const f2 cx2 = {cx,cx}, cy2 = {cy,cy}, cz2 = {cz,cz};
#pragma unroll
    for (int j = 0; j < PP2; ++j){
      const f2 dx = rx[j]-cx2, dy = ry[j]-cy2, dz = rz[j]-cz2;
      const f2 d = ((dx*dx) + (dy*dy)) + (dz*dz);
      mind[j].x = fminf(mind[j].x, d.x);
      mind[j].y = fminf(mind[j].y, d.y);
    }
    EXPUB((it+1) & 1)
  }
  __syncthreads();
  // epilogue: the only global stores
  for (int j = tid; j < M; j += NT){
    const float4 v = sp[WX[j]];
    O[3*j+0] = v.x; O[3*j+1] = v.y; O[3*j+2] = v.z;
  }
#undef EXPUB
#undef VALK
#undef XK
}

// ---------------------------------------------------------------------------
// top-4 (ascending) insertion + cross-lane merge helpers
// ---------------------------------------------------------------------------
__device__ __forceinline__ void top4_insert(u64& a0,u64& a1,u64& a2,u64& a3, u64 p){
  if (p < a3){
    const bool c2 = p < a2, c1 = p < a1, c0 = p < a0;
    const u64 n3 = c2 ? a2 : p;
    const u64 n2 = c2 ? (c1 ? a1 : p) : a2;
    const u64 n1 = c1 ? (c0 ? a0 : p) : a1;
    const u64 n0 = c0 ? p : a0;
    a0=n0; a1=n1; a2=n2; a3=n3;
  }
}

__device__ __forceinline__ void merge4(u64& a0, u64& a1, u64& a2, u64& a3, int st)
{
  const u64 b0 = shfl_xor64(a0, st);
  const u64 b1 = shfl_xor64(a1, st);
  const u64 b2 = shfl_xor64(a2, st);
  const u64 b3 = shfl_xor64(a3, st);
  const u64 m0 = umin64(a0, b3);
  const u64 m1 = umin64(a1, b2);
  const u64 m2 = umin64(a2, b1);
  const u64 m3 = umin64(a3, b0);
  const u64 lo02 = umin64(m0,m2), hi02 = umax64(m0,m2);
  const u64 lo13 = umin64(m1,m3), hi13 = umax64(m1,m3);
  a0 = umin64(lo02, lo13); a1 = umax64(lo02, lo13);
  a2 = umin64(hi02, hi13); a3 = umax64(hi02, hi13);
}

// ---------------------------------------------------------------------------
// Level-1: kNN(k=4) + MLP(3->8->16->16) + max over k -> f1
// ---------------------------------------------------------------------------
template<int N, int M, int CH>
__global__ __launch_bounds__(256)
void knn_mlp1_kernel(const float* __restrict__ q, const float* __restrict__ pts,
                     const float* __restrict__ w1, const float* __restrict__ b1,
                     const float* __restrict__ w2, const float* __restrict__ b2,
                     const float* __restrict__ w3, const float* __restrict__ b3,
                     float* __restrict__ f1)
{
  __shared__ float4 s4[CH];
  constexpr int QPB = 64;
  const int blk = blockIdx.x;
  const int b = blk / (M / QPB);
  const int chunk = blk % (M / QPB);
  const int tid = threadIdx.x;
  const int g = tid >> 2;
  const int r = tid & 3;
  const int qi = chunk * QPB + g;
  const float* qp = q + ((size_t)b * M + qi) * 3;
  const float qx = qp[0], qy = qp[1], qz = qp[2];
  const float sumq = rn_add(rn_add(rn_mul(qx,qx), rn_mul(qy,qy)), rn_mul(qz,qz));
  const float* P = pts + (size_t)b * N * 3;

  u64 a0=~0ull, a1=~0ull, a2=~0ull, a3=~0ull;
  for (int c0 = 0; c0 < N; c0 += CH){
    for (int i = tid; i < CH; i += 256){
      const float x = P[3*(c0+i)+0], y = P[3*(c0+i)+1], z = P[3*(c0+i)+2];
      s4[i] = make_float4(x, y, z,
          rn_add(rn_add(rn_mul(x,x), rn_mul(y,y)), rn_mul(z,z)));
    }
    __syncthreads();
#pragma unroll 4
    for (int jj = r; jj < CH; jj += 4){
      const float4 v = s4[jj];
      const float dot = rn_add(rn_add(rn_mul(qx,v.x), rn_mul(qy,v.y)),
                               rn_mul(qz,v.z));
      const float d = rn_add(rn_sub(sumq, rn_mul(2.0f, dot)), v.w);
      top4_insert(a0,a1,a2,a3, ((u64)fkey(d) << 32) | (u32)(c0+jj));
    }
    __syncthreads();
  }
  merge4(a0,a1,a2,a3,1);
  merge4(a0,a1,a2,a3,2);
  const u64 selp = (r==0) ? a0 : (r==1) ? a1 : (r==2) ? a2 : a3;
  const u32 nidx = (u32)selp;

  const float nx = P[3*nidx+0], ny = P[3*nidx+1], nz = P[3*nidx+2];
  float h1[8];
#pragma unroll
  for (int c = 0; c < 8; ++c){
    float acc = b1[c];
    acc = fmaf(nx, w1[0*8+c], acc);
    acc = fmaf(ny, w1[1*8+c], acc);
    acc = fmaf(nz, w1[2*8+c], acc);
    h1[c] = fmaxf(acc, 0.0f);
  }
  float h2[16];
#pragma unroll
  for (int c = 0; c < 16; ++c){
    float acc = b2[c];
#pragma unroll
    for (int k = 0; k < 8; ++k) acc = fmaf(h1[k], w2[k*16+c], acc);
    h2[c] = fmaxf(acc, 0.0f);
  }
  float* fo = f1 + ((size_t)b * M + qi) * 16;
#pragma unroll
  for (int c = 0; c < 16; ++c){
    float acc = b3[c];
#pragma unroll
    for (int k = 0; k < 16; ++k) acc = fmaf(h2[k], w3[k*16+c], acc);
    float v = fmaxf(acc, 0.0f);
    v = fmaxf(v, __shfl_xor(v, 1, 64));
    v = fmaxf(v, __shfl_xor(v, 2, 64));
    if (r == 0) fo[c] = v;
  }
}

// ---------------------------------------------------------------------------
// Level-2: kNN(k=4) over npts1 + gather f1 + MLP(16->32->64->64) + max -> f2
// Queries = first 512 rows of npts1 (FPS nesting property, exact).
// ---------------------------------------------------------------------------
__global__ __launch_bounds__(256)
void knn_mlp2_kernel(const float* __restrict__ q, const float* __restrict__ pts,
                     const float* __restrict__ f1,
                     const float* __restrict__ w1, const float* __restrict__ b1,
                     const float* __restrict__ w2, const float* __restrict__ b2,
                     const float* __restrict__ w3, const float* __restrict__ b3,
                     float* __restrict__ f2)
{
  constexpr int N = 2048, M = 512, QPB = 64, QSTR = 2048;
  __shared__ float4 s4[N];
  const int blk = blockIdx.x;
  const int b = blk / (M / QPB);
  const int chunk = blk % (M / QPB);
  const int tid = threadIdx.x;
  const int g = tid >> 2;
  const int r = tid & 3;
  const int qi = chunk * QPB + g;
  const float* qp = q + ((size_t)b * QSTR + qi) * 3;
  const float qx = qp[0], qy = qp[1], qz = qp[2];
  const float sumq = rn_add(rn_add(rn_mul(qx,qx), rn_mul(qy,qy)), rn_mul(qz,qz));
  const float* P = pts + (size_t)b * N * 3;

  for (int i = tid; i < N; i += 256){
    const float x = P[3*i+0], y = P[3*i+1], z = P[3*i+2];
    s4[i] = make_float4(x, y, z,
        rn_add(rn_add(rn_mul(x,x), rn_mul(y,y)), rn_mul(z,z)));
  }
  __syncthreads();

  u64 a0=~0ull, a1=~0ull, a2=~0ull, a3=~0ull;
#pragma unroll 4
  for (int j = r; j < N; j += 4){
    const float4 v = s4[j];
    const float dot = rn_add(rn_add(rn_mul(qx,v.x), rn_mul(qy,v.y)),
                             rn_mul(qz,v.z));
    const float d = rn_add(rn_sub(sumq, rn_mul(2.0f, dot)), v.w);
    top4_insert(a0,a1,a2,a3, ((u64)fkey(d) << 32) | (u32)j);
  }
  merge4(a0,a1,a2,a3,1);
  merge4(a0,a1,a2,a3,2);
  const u64 selp = (r==0) ? a0 : (r==1) ? a1 : (r==2) ? a2 : a3;
  const u32 nidx = (u32)selp;

  const float* fv = f1 + ((size_t)b * 2048 + nidx) * 16;
  float x[16];
#pragma unroll
  for (int i = 0; i < 4; ++i){
    const float4 v = ((const float4*)fv)[i];
    x[4*i+0]=v.x; x[4*i+1]=v.y; x[4*i+2]=v.z; x[4*i+3]=v.w;
  }
  float h1[32];
#pragma unroll
  for (int c = 0; c < 32; ++c){
    float acc = b1[c];
#pragma unroll
    for (int k = 0; k < 16; ++k) acc = fmaf(x[k], w1[k*32+c], acc);
    h1[c] = fmaxf(acc, 0.0f);
  }
  float h2[64];
#pragma unroll
  for (int c = 0; c < 64; ++c){
    float acc = b2[c];
#pragma unroll
    for (int k = 0; k < 32; ++k) acc = fmaf(h1[k], w2[k*64+c], acc);
    h2[c] = fmaxf(acc, 0.0f);
  }
  float* fo = f2 + ((size_t)b * M + qi) * 64;
#pragma unroll
  for (int c = 0; c < 64; ++c){
    float acc = b3[c];
#pragma unroll
    for (int k = 0; k < 64; ++k) acc = fmaf(h2[k], w3[k*64+c], acc);
    float v = fmaxf(acc, 0.0f);
    v = fmaxf(v, __shfl_xor(v, 1, 64));
    v = fmaxf(v, __shfl_xor(v, 2, 64));
    if (r == 0) fo[c] = v;
  }
}

// ---------------------------------------------------------------------------
// Level-3: MLP(64->128->256->256) on f2 + global max over 512 points/batch.
// ---------------------------------------------------------------------------
__global__ __launch_bounds__(256)
void mlp3_kernel(const float* __restrict__ f2,
                 const float* __restrict__ w1, const float* __restrict__ b1,
                 const float* __restrict__ w2, const float* __restrict__ b2,
                 const float* __restrict__ w3, const float* __restrict__ b3,
                 float* __restrict__ out)
{
  constexpr int P = 16;
  __shared__ float X [P][64];
  __shared__ float H1[P][128];
  __shared__ float H2[P][256];
  __shared__ float PM[4][256];
  const int blk = blockIdx.x;
  const int b  = blk >> 5;
  const int pc = blk & 31;
  const int tid = threadIdx.x;
  const float* F = f2 + ((size_t)b * 512 + (size_t)pc * P) * 64;
  { const float4 v = ((const float4*)F)[tid]; ((float4*)&X[0][0])[tid] = v; }
  __syncthreads();
  {
    const int p = tid >> 4, c0 = (tid & 15) * 8;
    float acc[8];
#pragma unroll
    for (int i = 0; i < 8; ++i) acc[i] = b1[c0+i];
    for (int k = 0; k < 64; ++k){
      const float xv = X[p][k];
      const float4 wa = *(const float4*)&w1[k*128 + c0];
      const float4 wb = *(const float4*)&w1[k*128 + c0 + 4];
      acc[0]=fmaf(xv,wa.x,acc[0]); acc[1]=fmaf(xv,wa.y,acc[1]);
      acc[2]=fmaf(xv,wa.z,acc[2]); acc[3]=fmaf(xv,wa.w,acc[3]);
      acc[4]=fmaf(xv,wb.x,acc[4]); acc[5]=fmaf(xv,wb.y,acc[5]);
      acc[6]=fmaf(xv,wb.z,acc[6]); acc[7]=fmaf(xv,wb.w,acc[7]);
    }
#pragma unroll
    for (int i = 0; i < 8; ++i) H1[p][c0+i] = fmaxf(acc[i], 0.0f);
  }
  __syncthreads();
  {
    const int p = tid >> 4, c0 = (tid & 15) * 16;
    float acc[16];
#pragma unroll
    for (int i = 0; i < 16; ++i) acc[i] = b2[c0+i];
    for (int k = 0; k < 128; ++k){
      const float xv = H1[p][k];
#pragma unroll
      for (int i4 = 0; i4 < 4; ++i4){
        const float4 wv = *(const float4*)&w2[k*256 + c0 + 4*i4];
        acc[4*i4+0]=fmaf(xv,wv.x,acc[4*i4+0]);
        acc[4*i4+1]=fmaf(xv,wv.y,acc[4*i4+1]);
        acc[4*i4+2]=fmaf(xv,wv.z,acc[4*i4+2]);
        acc[4*i4+3]=fmaf(xv,wv.w,acc[4*i4+3]);
      }
    }
#pragma unroll
    for (int i = 0; i < 16; ++i) H2[p][c0+i] = fmaxf(acc[i], 0.0f);
  }
  __syncthreads();
  {
    const int pg = tid >> 6, c0 = (tid & 63) * 4;
    float acc[4][4];
#pragma unroll
    for (int p4 = 0; p4 < 4; ++p4)
#pragma unroll
      for (int i = 0; i < 4; ++i) acc[p4][i] = b3[c0+i];
    for (int k = 0; k < 256; ++k){
      const float4 wv = *(const float4*)&w3[k*256 + c0];
#pragma unroll
      for (int p4 = 0; p4 < 4; ++p4){
        const float xv = H2[pg*4+p4][k];
        acc[p4][0]=fmaf(xv,wv.x,acc[p4][0]);
        acc[p4][1]=fmaf(xv,wv.y,acc[p4][1]);
        acc[p4][2]=fmaf(xv,wv.z,acc[p4][2]);
        acc[p4][3]=fmaf(xv,wv.w,acc[p4][3]);
      }
    }
    float4 mx;
    mx.x = fmaxf(fmaxf(fmaxf(acc[0][0],0.f),fmaxf(acc[1][0],0.f)),
                 fmaxf(fmaxf(acc[2][0],0.f),fmaxf(acc[3][0],0.f)));
    mx.y = fmaxf(fmaxf(fmaxf(acc[0][1],0.f),fmaxf(acc[1][1],0.f)),
                 fmaxf(fmaxf(acc[2][1],0.f),fmaxf(acc[3][1],0.f)));
    mx.z = fmaxf(fmaxf(fmaxf(acc[0][2],0.f),fmaxf(acc[1][2],0.f)),
                 fmaxf(fmaxf(acc[2][2],0.f),fmaxf(acc[3][2],0.f)));
    mx.w = fmaxf(fmaxf(fmaxf(acc[0][3],0.f),fmaxf(acc[1][3],0.f)),
                 fmaxf(fmaxf(acc[2][3],0.f),fmaxf(acc[3][3],0.f)));
    *(float4*)&PM[pg][c0] = mx;
  }
  __syncthreads();
  {
    const float m = fmaxf(fmaxf(PM[0][tid], PM[1][tid]),
                          fmaxf(PM[2][tid], PM[3][tid]));
    atomicMax((int*)(out + b*256 + tid), __float_as_int(m));
  }
}

// ---------------------------------------------------------------------------
extern "C" void kernel_launch(void* const* d_in, const int* in_sizes, int n_in,
                              void* d_out, int out_size, void* d_ws, size_t ws_size,
                              hipStream_t stream)
{
  const float* pts  = (const float*)d_in[0];
  // d_in[1] = batch (int64) -- implied by uniform layout, unused
  const float* p1w1 = (const float*)d_in[2];
  const float* p1b1 = (const float*)d_in[3];
  const float* p1w2 = (const float*)d_in[4];
  const float* p1b2 = (const float*)d_in[5];
  const float* p1w3 = (const float*)d_in[6];
  const float* p1b3 = (const float*)d_in[7];
  const float* p2w1 = (const float*)d_in[8];
  const float* p2b1 = (const float*)d_in[9];
  const float* p2w2 = (const float*)d_in[10];
  const float* p2b2 = (const float*)d_in[11];
  const float* p2w3 = (const float*)d_in[12];
  const float* p2b3 = (const float*)d_in[13];
  const float* p3w1 = (const float*)d_in[14];
  const float* p3b1 = (const float*)d_in[15];
  const float* p3w2 = (const float*)d_in[16];
  const float* p3b2 = (const float*)d_in[17];
  const float* p3w3 = (const float*)d_in[18];
  const float* p3b3 = (const float*)d_in[19];

  float* ws = (float*)d_ws;
  size_t o = 0;
  float* npts1 = ws + o; o += (size_t)8*2048*3;
  float* f1    = ws + o; o += (size_t)8*2048*16;
  float* f2    = ws + o; o += (size_t)8*512*64;

  fps_kernel<8192,512,2048><<<8, 512, 0, stream>>>(pts, npts1);
  knn_mlp1_kernel<8192,2048,2048><<<8*32, 256, 0, stream>>>(npts1, pts,
      p1w1, p1b1, p1w2, p1b2, p1w3, p1b3, f1);
  // fps level-2 eliminated: fps(npts1,512) == npts1[:512] (nesting property)
  knn_mlp2_kernel<<<8*8, 256, 0, stream>>>(npts1, npts1, f1,
      p2w1, p2b1, p2w2, p2b2, p2w3, p2b3, f2);
  hipMemsetAsync(d_out, 0, (size_t)out_size * sizeof(float), stream);
  mlp3_kernel<<<8*32, 256, 0, stream>>>(f2,
      p3w1, p3b1, p3w2, p3b2, p3w3, p3b3, (float*)d_out);
}

// Round 11
// 2252.450 us; speedup vs baseline: 1.2917x; 1.2917x over previous
//
#include <hip/hip_runtime.h>
#include <stdint.h>

typedef unsigned long long u64;
typedef unsigned int u32;
typedef float f2 __attribute__((ext_vector_type(2)));

__device__ __forceinline__ float rn_mul(float a, float b){ return __fmul_rn(a,b); }
__device__ __forceinline__ float rn_add(float a, float b){ return __fadd_rn(a,b); }
__device__ __forceinline__ float rn_sub(float a, float b){ return __fsub_rn(a,b); }

// monotone float->uint key (for knn; handles tiny negative cancellation)
__device__ __forceinline__ u32 fkey(float d){
  u32 b = __float_as_uint(d);
  return b ^ ((u32)((int)b >> 31) | 0x80000000u);
}

__device__ __forceinline__ u64 shfl_xor64(u64 v, int mask){
  int lo = __shfl_xor((int)(u32)v, mask, 64);
  int hi = __shfl_xor((int)(u32)(v >> 32), mask, 64);
  return ((u64)(u32)hi << 32) | (u32)lo;
}
__device__ __forceinline__ u64 umin64(u64 a, u64 b){ return a < b ? a : b; }
__device__ __forceinline__ u64 umax64(u64 a, u64 b){ return a > b ? a : b; }

// ---- 64-bit DPP max (old=src: invalid/shifted-in lanes harmless) ----------
template<int C>
__device__ __forceinline__ u64 dstep64(u64 v){
  const u32 l = (u32)__builtin_amdgcn_update_dpp((int)(u32)v, (int)(u32)v, C, 0xF, 0xF, false);
  const u32 h = (u32)__builtin_amdgcn_update_dpp((int)(u32)(v>>32), (int)(u32)(v>>32), C, 0xF, 0xF, false);
  const u64 o = ((u64)h << 32) | l;
  return o > v ? o : v;
}
// full-wave max: valid result in lane 63
__device__ __forceinline__ u64 wave64_max64(u64 v){
  v = dstep64<0x111>(v);  // row_shr:1
  v = dstep64<0x112>(v);  // row_shr:2
  v = dstep64<0x114>(v);  // row_shr:4
  v = dstep64<0x118>(v);  // row_shr:8
  v = dstep64<0x142>(v);  // row_bcast:15
  v = dstep64<0x143>(v);  // row_bcast:31
  return v;
}
// max over lanes 0..7 -> uniform value (via readlane broadcast)
__device__ __forceinline__ u64 red8_max64(u64 v){
  v = dstep64<0x111>(v);
  v = dstep64<0x112>(v);
  v = dstep64<0x114>(v);
  const u32 l = (u32)__builtin_amdgcn_readlane((int)(u32)v, 7);
  const u32 h = (u32)__builtin_amdgcn_readlane((int)(u32)(v>>32), 7);
  return ((u64)h << 32) | l;
}

__device__ __forceinline__ f2 f2max(f2 a, f2 b){
  f2 r; r.x = fmaxf(a.x,b.x); r.y = fmaxf(a.y,b.y); return r;
}

// ---------------------------------------------------------------------------
// FPS: one block per batch, full cloud, 16 pts/thread f2-packed in registers.
// Per iter: fused update+max -> local first-idx rescan -> ONE combined 64-bit
// DPP wave reduce ((valbits<<32)|~gidx) -> lane63 publishes u64 -> barrier ->
// b64 read + 3-step u64 DPP red8 -> coords via one b128 LDS broadcast.
// No global ops in the loop; winners to LDS u16 list, stored in epilogue.
// Tie semantics = jnp.argmax (max value, smallest index) exactly.
// Structural floor (measured r1-r10): ~2170 cyc/iter serial chain; issue-,
// DPP-depth-, and LDS-read-count-invariant. Best-known configuration.
// ---------------------------------------------------------------------------
template<int N, int NT, int M>
__global__ __launch_bounds__(NT)
void fps_kernel(const float* __restrict__ pts, float* __restrict__ npts)
{
#pragma clang fp contract(off)
  constexpr int PPT = N / NT;          // 16
  constexpr int PP2 = PPT / 2;         // 8
  constexpr int NW  = NT / 64;         // 8
  __shared__ float4 sp[N];             // 128 KB coord table
  __shared__ unsigned short WX[M];     // winner idx per iteration
  __shared__ u64 part[2][NW];
  const int b = blockIdx.x;
  const float* P = pts + (size_t)b * N * 3;
  float* O = npts + (size_t)b * M * 3;
  const int tid = threadIdx.x, lane = tid & 63, wv = tid >> 6;

  for (int i = tid; i < N; i += NT)
    sp[i] = make_float4(P[3*i+0], P[3*i+1], P[3*i+2], 0.0f);
  if (tid == 0) WX[0] = 0;
  __syncthreads();

  f2 rx[PP2], ry[PP2], rz[PP2], mind[PP2];
  const float4 c0 = sp[0];
  float bm;
  {
    const f2 cx2 = {c0.x,c0.x}, cy2 = {c0.y,c0.y}, cz2 = {c0.z,c0.z};
    f2 t[PP2];
#pragma unroll
    for (int j = 0; j < PP2; ++j){
      const float4 va = sp[tid + (2*j+0)*NT];
      const float4 vb = sp[tid + (2*j+1)*NT];
      rx[j] = f2{va.x, vb.x}; ry[j] = f2{va.y, vb.y}; rz[j] = f2{va.z, vb.z};
      const f2 dx = rx[j]-cx2, dy = ry[j]-cy2, dz = rz[j]-cz2;
      mind[j] = ((dx*dx) + (dy*dy)) + (dz*dz);   // v_pk_*, IEEE rn
      t[j] = mind[j];
    }
#pragma unroll
    for (int s = PP2/2; s > 0; s >>= 1)
#pragma unroll
      for (int i = 0; i < s; ++i) t[i] = f2max(t[i], t[i+s]);
    bm = fmaxf(t[0].x, t[0].y);
  }

  // lane candidate: (value bits << 32) | ~min matching global idx
#define LANECAND(dst)                                                         \
  {                                                                           \
    u32 mo = 0xFFFFFFFFu;                                                     \
    _Pragma("unroll")                                                         \
    for (int j = PP2-1; j >= 0; --j){                                         \
      const u32 gb = (u32)(tid + (2*j+1)*NT);                                 \
      const u32 ga = (u32)(tid + (2*j+0)*NT);                                 \
      if (mind[j].y == bm) mo = gb;                                           \
      if (mind[j].x == bm) mo = ga;                                           \
    }                                                                         \
    (dst) = ((u64)__float_as_uint(bm) << 32) | (u64)(u32)~mo;                 \
  }

  u64 mypk;
  { u64 c; LANECAND(c); mypk = wave64_max64(c); }

  for (int it = 1; it < M; ++it){
    if (lane == 63) part[it & 1][wv] = mypk;
    __syncthreads();                   // LDS-only loop
    const u64 best = red8_max64(part[it & 1][lane & (NW-1)]);
    const u32 widx = ~(u32)best;
    if (tid == 0) WX[it] = (unsigned short)widx;
    const float4 c = sp[widx];         // single b128 broadcast read
    const f2 cx2 = {c.x,c.x}, cy2 = {c.y,c.y}, cz2 = {c.z,c.z};
    f2 t[PP2];
#pragma unroll
    for (int j = 0; j < PP2; ++j){
      const f2 dx = rx[j]-cx2, dy = ry[j]-cy2, dz = rz[j]-cz2;
      const f2 d = ((dx*dx) + (dy*dy)) + (dz*dz);
      mind[j].x = fminf(mind[j].x, d.x);
      mind[j].y = fminf(mind[j].y, d.y);
      t[j] = mind[j];
    }
#pragma unroll
    for (int s = PP2/2; s > 0; s >>= 1)
#pragma unroll
      for (int i = 0; i < s; ++i) t[i] = f2max(t[i], t[i+s]);
    bm = fmaxf(t[0].x, t[0].y);
    u64 cand; LANECAND(cand);
    mypk = wave64_max64(cand);
  }
  __syncthreads();
  // epilogue: the only global stores
  for (int j = tid; j < M; j += NT){
    const float4 v = sp[WX[j]];
    O[3*j+0] = v.x; O[3*j+1] = v.y; O[3*j+2] = v.z;
  }
#undef LANECAND
}

// ---------------------------------------------------------------------------
// top-4 (ascending) insertion + cross-lane merge helpers
// ---------------------------------------------------------------------------
__device__ __forceinline__ void top4_insert(u64& a0,u64& a1,u64& a2,u64& a3, u64 p){
  if (p < a3){
    const bool c2 = p < a2, c1 = p < a1, c0 = p < a0;
    const u64 n3 = c2 ? a2 : p;
    const u64 n2 = c2 ? (c1 ? a1 : p) : a2;
    const u64 n1 = c1 ? (c0 ? a0 : p) : a1;
    const u64 n0 = c0 ? p : a0;
    a0=n0; a1=n1; a2=n2; a3=n3;
  }
}

__device__ __forceinline__ void merge4(u64& a0, u64& a1, u64& a2, u64& a3, int st)
{
  const u64 b0 = shfl_xor64(a0, st);
  const u64 b1 = shfl_xor64(a1, st);
  const u64 b2 = shfl_xor64(a2, st);
  const u64 b3 = shfl_xor64(a3, st);
  const u64 m0 = umin64(a0, b3);
  const u64 m1 = umin64(a1, b2);
  const u64 m2 = umin64(a2, b1);
  const u64 m3 = umin64(a3, b0);
  const u64 lo02 = umin64(m0,m2), hi02 = umax64(m0,m2);
  const u64 lo13 = umin64(m1,m3), hi13 = umax64(m1,m3);
  a0 = umin64(lo02, lo13); a1 = umax64(lo02, lo13);
  a2 = umin64(hi02, hi13); a3 = umax64(hi02, hi13);
}

// ---------------------------------------------------------------------------
// Level-1: kNN(k=4) + MLP(3->8->16->16) + max over k -> f1
// ---------------------------------------------------------------------------
template<int N, int M, int CH>
__global__ __launch_bounds__(256)
void knn_mlp1_kernel(const float* __restrict__ q, const float* __restrict__ pts,
                     const float* __restrict__ w1, const float* __restrict__ b1,
                     const float* __restrict__ w2, const float* __restrict__ b2,
                     const float* __restrict__ w3, const float* __restrict__ b3,
                     float* __restrict__ f1)
{
  __shared__ float4 s4[CH];
  constexpr int QPB = 64;
  const int blk = blockIdx.x;
  const int b = blk / (M / QPB);
  const int chunk = blk % (M / QPB);
  const int tid = threadIdx.x;
  const int g = tid >> 2;
  const int r = tid & 3;
  const int qi = chunk * QPB + g;
  const float* qp = q + ((size_t)b * M + qi) * 3;
  const float qx = qp[0], qy = qp[1], qz = qp[2];
  const float sumq = rn_add(rn_add(rn_mul(qx,qx), rn_mul(qy,qy)), rn_mul(qz,qz));
  const float* P = pts + (size_t)b * N * 3;

  u64 a0=~0ull, a1=~0ull, a2=~0ull, a3=~0ull;
  for (int c0 = 0; c0 < N; c0 += CH){
    for (int i = tid; i < CH; i += 256){
      const float x = P[3*(c0+i)+0], y = P[3*(c0+i)+1], z = P[3*(c0+i)+2];
      s4[i] = make_float4(x, y, z,
          rn_add(rn_add(rn_mul(x,x), rn_mul(y,y)), rn_mul(z,z)));
    }
    __syncthreads();
#pragma unroll 4
    for (int jj = r; jj < CH; jj += 4){
      const float4 v = s4[jj];
      const float dot = rn_add(rn_add(rn_mul(qx,v.x), rn_mul(qy,v.y)),
                               rn_mul(qz,v.z));
      const float d = rn_add(rn_sub(sumq, rn_mul(2.0f, dot)), v.w);
      top4_insert(a0,a1,a2,a3, ((u64)fkey(d) << 32) | (u32)(c0+jj));
    }
    __syncthreads();
  }
  merge4(a0,a1,a2,a3,1);
  merge4(a0,a1,a2,a3,2);
  const u64 selp = (r==0) ? a0 : (r==1) ? a1 : (r==2) ? a2 : a3;
  const u32 nidx = (u32)selp;

  const float nx = P[3*nidx+0], ny = P[3*nidx+1], nz = P[3*nidx+2];
  float h1[8];
#pragma unroll
  for (int c = 0; c < 8; ++c){
    float acc = b1[c];
    acc = fmaf(nx, w1[0*8+c], acc);
    acc = fmaf(ny, w1[1*8+c], acc);
    acc = fmaf(nz, w1[2*8+c], acc);
    h1[c] = fmaxf(acc, 0.0f);
  }
  float h2[16];
#pragma unroll
  for (int c = 0; c < 16; ++c){
    float acc = b2[c];
#pragma unroll
    for (int k = 0; k < 8; ++k) acc = fmaf(h1[k], w2[k*16+c], acc);
    h2[c] = fmaxf(acc, 0.0f);
  }
  float* fo = f1 + ((size_t)b * M + qi) * 16;
#pragma unroll
  for (int c = 0; c < 16; ++c){
    float acc = b3[c];
#pragma unroll
    for (int k = 0; k < 16; ++k) acc = fmaf(h2[k], w3[k*16+c], acc);
    float v = fmaxf(acc, 0.0f);
    v = fmaxf(v, __shfl_xor(v, 1, 64));
    v = fmaxf(v, __shfl_xor(v, 2, 64));
    if (r == 0) fo[c] = v;
  }
}

// ---------------------------------------------------------------------------
// Level-2: kNN(k=4) over npts1 + gather f1 + MLP(16->32->64->64) + max -> f2
// Queries = first 512 rows of npts1 (FPS nesting property, exact).
// ---------------------------------------------------------------------------
__global__ __launch_bounds__(256)
void knn_mlp2_kernel(const float* __restrict__ q, const float* __restrict__ pts,
                     const float* __restrict__ f1,
                     const float* __restrict__ w1, const float* __restrict__ b1,
                     const float* __restrict__ w2, const float* __restrict__ b2,
                     const float* __restrict__ w3, const float* __restrict__ b3,
                     float* __restrict__ f2)
{
  constexpr int N = 2048, M = 512, QPB = 64, QSTR = 2048;
  __shared__ float4 s4[N];
  const int blk = blockIdx.x;
  const int b = blk / (M / QPB);
  const int chunk = blk % (M / QPB);
  const int tid = threadIdx.x;
  const int g = tid >> 2;
  const int r = tid & 3;
  const int qi = chunk * QPB + g;
  const float* qp = q + ((size_t)b * QSTR + qi) * 3;
  const float qx = qp[0], qy = qp[1], qz = qp[2];
  const float sumq = rn_add(rn_add(rn_mul(qx,qx), rn_mul(qy,qy)), rn_mul(qz,qz));
  const float* P = pts + (size_t)b * N * 3;

  for (int i = tid; i < N; i += 256){
    const float x = P[3*i+0], y = P[3*i+1], z = P[3*i+2];
    s4[i] = make_float4(x, y, z,
        rn_add(rn_add(rn_mul(x,x), rn_mul(y,y)), rn_mul(z,z)));
  }
  __syncthreads();

  u64 a0=~0ull, a1=~0ull, a2=~0ull, a3=~0ull;
#pragma unroll 4
  for (int j = r; j < N; j += 4){
    const float4 v = s4[j];
    const float dot = rn_add(rn_add(rn_mul(qx,v.x), rn_mul(qy,v.y)),
                             rn_mul(qz,v.z));
    const float d = rn_add(rn_sub(sumq, rn_mul(2.0f, dot)), v.w);
    top4_insert(a0,a1,a2,a3, ((u64)fkey(d) << 32) | (u32)j);
  }
  merge4(a0,a1,a2,a3,1);
  merge4(a0,a1,a2,a3,2);
  const u64 selp = (r==0) ? a0 : (r==1) ? a1 : (r==2) ? a2 : a3;
  const u32 nidx = (u32)selp;

  const float* fv = f1 + ((size_t)b * 2048 + nidx) * 16;
  float x[16];
#pragma unroll
  for (int i = 0; i < 4; ++i){
    const float4 v = ((const float4*)fv)[i];
    x[4*i+0]=v.x; x[4*i+1]=v.y; x[4*i+2]=v.z; x[4*i+3]=v.w;
  }
  float h1[32];
#pragma unroll
  for (int c = 0; c < 32; ++c){
    float acc = b1[c];
#pragma unroll
    for (int k = 0; k < 16; ++k) acc = fmaf(x[k], w1[k*32+c], acc);
    h1[c] = fmaxf(acc, 0.0f);
  }
  float h2[64];
#pragma unroll
  for (int c = 0; c < 64; ++c){
    float acc = b2[c];
#pragma unroll
    for (int k = 0; k < 32; ++k) acc = fmaf(h1[k], w2[k*64+c], acc);
    h2[c] = fmaxf(acc, 0.0f);
  }
  float* fo = f2 + ((size_t)b * M + qi) * 64;
#pragma unroll
  for (int c = 0; c < 64; ++c){
    float acc = b3[c];
#pragma unroll
    for (int k = 0; k < 64; ++k) acc = fmaf(h2[k], w3[k*64+c], acc);
    float v = fmaxf(acc, 0.0f);
    v = fmaxf(v, __shfl_xor(v, 1, 64));
    v = fmaxf(v, __shfl_xor(v, 2, 64));
    if (r == 0) fo[c] = v;
  }
}

// ---------------------------------------------------------------------------
// Level-3: MLP(64->128->256->256) on f2 + global max over 512 points/batch.
// ---------------------------------------------------------------------------
__global__ __launch_bounds__(256)
void mlp3_kernel(const float* __restrict__ f2,
                 const float* __restrict__ w1, const float* __restrict__ b1,
                 const float* __restrict__ w2, const float* __restrict__ b2,
                 const float* __restrict__ w3, const float* __restrict__ b3,
                 float* __restrict__ out)
{
  constexpr int P = 16;
  __shared__ float X [P][64];
  __shared__ float H1[P][128];
  __shared__ float H2[P][256];
  __shared__ float PM[4][256];
  const int blk = blockIdx.x;
  const int b  = blk >> 5;
  const int pc = blk & 31;
  const int tid = threadIdx.x;
  const float* F = f2 + ((size_t)b * 512 + (size_t)pc * P) * 64;
  { const float4 v = ((const float4*)F)[tid]; ((float4*)&X[0][0])[tid] = v; }
  __syncthreads();
  {
    const int p = tid >> 4, c0 = (tid & 15) * 8;
    float acc[8];
#pragma unroll
    for (int i = 0; i < 8; ++i) acc[i] = b1[c0+i];
    for (int k = 0; k < 64; ++k){
      const float xv = X[p][k];
      const float4 wa = *(const float4*)&w1[k*128 + c0];
      const float4 wb = *(const float4*)&w1[k*128 + c0 + 4];
      acc[0]=fmaf(xv,wa.x,acc[0]); acc[1]=fmaf(xv,wa.y,acc[1]);
      acc[2]=fmaf(xv,wa.z,acc[2]); acc[3]=fmaf(xv,wa.w,acc[3]);
      acc[4]=fmaf(xv,wb.x,acc[4]); acc[5]=fmaf(xv,wb.y,acc[5]);
      acc[6]=fmaf(xv,wb.z,acc[6]); acc[7]=fmaf(xv,wb.w,acc[7]);
    }
#pragma unroll
    for (int i = 0; i < 8; ++i) H1[p][c0+i] = fmaxf(acc[i], 0.0f);
  }
  __syncthreads();
  {
    const int p = tid >> 4, c0 = (tid & 15) * 16;
    float acc[16];
#pragma unroll
    for (int i = 0; i < 16; ++i) acc[i] = b2[c0+i];
    for (int k = 0; k < 128; ++k){
      const float xv = H1[p][k];
#pragma unroll
      for (int i4 = 0; i4 < 4; ++i4){
        const float4 wv = *(const float4*)&w2[k*256 + c0 + 4*i4];
        acc[4*i4+0]=fmaf(xv,wv.x,acc[4*i4+0]);
        acc[4*i4+1]=fmaf(xv,wv.y,acc[4*i4+1]);
        acc[4*i4+2]=fmaf(xv,wv.z,acc[4*i4+2]);
        acc[4*i4+3]=fmaf(xv,wv.w,acc[4*i4+3]);
      }
    }
#pragma unroll
    for (int i = 0; i < 16; ++i) H2[p][c0+i] = fmaxf(acc[i], 0.0f);
  }
  __syncthreads();
  {
    const int pg = tid >> 6, c0 = (tid & 63) * 4;
    float acc[4][4];
#pragma unroll
    for (int p4 = 0; p4 < 4; ++p4)
#pragma unroll
      for (int i = 0; i < 4; ++i) acc[p4][i] = b3[c0+i];
    for (int k = 0; k < 256; ++k){
      const float4 wv = *(const float4*)&w3[k*256 + c0];
#pragma unroll
      for (int p4 = 0; p4 < 4; ++p4){
        const float xv = H2[pg*4+p4][k];
        acc[p4][0]=fmaf(xv,wv.x,acc[p4][0]);
        acc[p4][1]=fmaf(xv,wv.y,acc[p4][1]);
        acc[p4][2]=fmaf(xv,wv.z,acc[p4][2]);
        acc[p4][3]=fmaf(xv,wv.w,acc[p4][3]);
      }
    }
    float4 mx;
    mx.x = fmaxf(fmaxf(fmaxf(acc[0][0],0.f),fmaxf(acc[1][0],0.f)),
                 fmaxf(fmaxf(acc[2][0],0.f),fmaxf(acc[3][0],0.f)));
    mx.y = fmaxf(fmaxf(fmaxf(acc[0][1],0.f),fmaxf(acc[1][1],0.f)),
                 fmaxf(fmaxf(acc[2][1],0.f),fmaxf(acc[3][1],0.f)));
    mx.z = fmaxf(fmaxf(fmaxf(acc[0][2],0.f),fmaxf(acc[1][2],0.f)),
                 fmaxf(fmaxf(acc[2][2],0.f),fmaxf(acc[3][2],0.f)));
    mx.w = fmaxf(fmaxf(fmaxf(acc[0][3],0.f),fmaxf(acc[1][3],0.f)),
                 fmaxf(fmaxf(acc[2][3],0.f),fmaxf(acc[3][3],0.f)));
    *(float4*)&PM[pg][c0] = mx;
  }
  __syncthreads();
  {
    const float m = fmaxf(fmaxf(PM[0][tid], PM[1][tid]),
                          fmaxf(PM[2][tid], PM[3][tid]));
    atomicMax((int*)(out + b*256 + tid), __float_as_int(m));
  }
}

// ---------------------------------------------------------------------------
extern "C" void kernel_launch(void* const* d_in, const int* in_sizes, int n_in,
                              void* d_out, int out_size, void* d_ws, size_t ws_size,
                              hipStream_t stream)
{
  const float* pts  = (const float*)d_in[0];
  // d_in[1] = batch (int64) -- implied by uniform layout, unused
  const float* p1w1 = (const float*)d_in[2];
  const float* p1b1 = (const float*)d_in[3];
  const float* p1w2 = (const float*)d_in[4];
  const float* p1b2 = (const float*)d_in[5];
  const float* p1w3 = (const float*)d_in[6];
  const float* p1b3 = (const float*)d_in[7];
  const float* p2w1 = (const float*)d_in[8];
  const float* p2b1 = (const float*)d_in[9];
  const float* p2w2 = (const float*)d_in[10];
  const float* p2b2 = (const float*)d_in[11];
  const float* p2w3 = (const float*)d_in[12];
  const float* p2b3 = (const float*)d_in[13];
  const float* p3w1 = (const float*)d_in[14];
  const float* p3b1 = (const float*)d_in[15];
  const float* p3w2 = (const float*)d_in[16];
  const float* p3b2 = (const float*)d_in[17];
  const float* p3w3 = (const float*)d_in[18];
  const float* p3b3 = (const float*)d_in[19];

  float* ws = (float*)d_ws;
  size_t o = 0;
  float* npts1 = ws + o; o += (size_t)8*2048*3;
  float* f1    = ws + o; o += (size_t)8*2048*16;
  float* f2    = ws + o; o += (size_t)8*512*64;

  fps_kernel<8192,512,2048><<<8, 512, 0, stream>>>(pts, npts1);
  knn_mlp1_kernel<8192,2048,2048><<<8*32, 256, 0, stream>>>(npts1, pts,
      p1w1, p1b1, p1w2, p1b2, p1w3, p1b3, f1);
  // fps level-2 eliminated: fps(npts1,512) == npts1[:512] (nesting property)
  knn_mlp2_kernel<<<8*8, 256, 0, stream>>>(npts1, npts1, f1,
      p2w1, p2b1, p2w2, p2b2, p2w3, p2b3, f2);
  hipMemsetAsync(d_out, 0, (size_t)out_size * sizeof(float), stream);
  mlp3_kernel<<<8*32, 256, 0, stream>>>(f2,
      p3w1, p3b1, p3w2, p3b2, p3w3, p3b3, (float*)d_out);
}